// Round 1
// baseline (9.391 us; speedup 1.0000x reference)
//
#include <hip/hip_runtime.h>

#define WIDTH 64
#define HW (WIDTH * WIDTH)   // 4096
#define BATCH 16
#define NOUT (HW * BATCH)    // 65536

// y[(yo,xo), b] = sigmoid( sum over (dy,dx) in [-1,1]^2 of
//                          w[k][(yo-dy,xo-dx)] * x[(yo-dy,xo-dx), b] )
// where k = (dx+1)*3 + (dy+1)  (Python: dx outer, dy inner).
// network[] input is a deterministic shift mask — never read.
__global__ __launch_bounds__(256) void BCNLayer_kernel(
        const float* __restrict__ x,      // (HW, BATCH)
        const float* __restrict__ w,      // (K, HW, 1)
        float* __restrict__ out) {        // (HW, BATCH)
    int idx = blockIdx.x * blockDim.x + threadIdx.x;
    if (idx >= NOUT) return;
    int b  = idx & (BATCH - 1);
    int i  = idx >> 4;          // output neuron linear index
    int xo = i & (WIDTH - 1);
    int yo = i >> 6;

    float acc = 0.0f;
#pragma unroll
    for (int dx = -1; dx <= 1; ++dx) {
#pragma unroll
        for (int dy = -1; dy <= 1; ++dy) {
            int xi = xo - dx;
            int yi = yo - dy;
            if ((unsigned)xi < (unsigned)WIDTH && (unsigned)yi < (unsigned)WIDTH) {
                int k = (dx + 1) * 3 + (dy + 1);
                int j = xi + WIDTH * yi;
                acc += w[k * HW + j] * x[j * BATCH + b];
            }
        }
    }
    // sigmoid
    out[idx] = 1.0f / (1.0f + __expf(-acc));
}

extern "C" void kernel_launch(void* const* d_in, const int* in_sizes, int n_in,
                              void* d_out, int out_size, void* d_ws, size_t ws_size,
                              hipStream_t stream) {
    const float* x = (const float*)d_in[0];   // (HW, BATCH) f32
    const float* w = (const float*)d_in[1];   // (K, HW, 1) f32
    // d_in[2] = network, deterministic shift masks — unused.
    float* out = (float*)d_out;

    int threads = 256;
    int blocks = (NOUT + threads - 1) / threads;  // 256
    BCNLayer_kernel<<<blocks, threads, 0, stream>>>(x, w, out);
}